// Round 1
// baseline (637.810 us; speedup 1.0000x reference)
//
#include <hip/hip_runtime.h>
#include <math.h>

#define T_DIM 16384
#define A_DIM 128
#define K_DIM 128
#define N_STEPS 16
#define E_DIM 126
#define NSEQ 4

// fm kernel tiling
#define AT 32                                   // atoms per block
#define TT 512                                  // time samples per block
#define NB_PER_SEQ ((A_DIM / AT) * (T_DIM / TT)) // 4 * 32 = 128

// ---------------------------------------------------------------------------
// d_unit = d / (||d_row|| + 1e-8)
__global__ void k_dunit(const float* __restrict__ d, float* __restrict__ du) {
    int a = blockIdx.x;
    int k = threadIdx.x;
    float v = d[a * K_DIM + k];
    __shared__ float s[K_DIM];
    s[k] = v * v;
    __syncthreads();
    for (int off = K_DIM / 2; off > 0; off >>= 1) {
        if (k < off) s[k] += s[k + off];
        __syncthreads();
    }
    float norm = sqrtf(s[0]) + 1e-8f;
    du[a * K_DIM + k] = v / norm;
}

// res[0:2T] = a, res[2T:4T] = b
__global__ void k_init(const float* __restrict__ a, const float* __restrict__ b,
                       float* __restrict__ res) {
    int i = blockIdx.x * blockDim.x + threadIdx.x;
    if (i < 2 * T_DIM) res[i] = a[i];
    else if (i < 4 * T_DIM) res[i] = b[i - 2 * T_DIM];
}

// ---------------------------------------------------------------------------
// fm[a,t] = sum_k res[t-64+k] * du[a,k]; per-block argmax (lowest index wins ties)
__global__ __launch_bounds__(256) void k_fm_argmax(
    const float* __restrict__ res, const float* __restrict__ du,
    float* __restrict__ pvals, int* __restrict__ pidx) {
    int seq = blockIdx.y;
    int blk = blockIdx.x;                 // [0, NB_PER_SEQ)
    int atile = blk / (T_DIM / TT);       // 0..3
    int ttile = blk % (T_DIM / TT);       // 0..31
    int a_base = atile * AT;
    int t_base = ttile * TT;

    __shared__ float du_sh[AT * K_DIM];        // 16 KB
    __shared__ float res_sh[TT + K_DIM];       // 2.5 KB (639 used)
    __shared__ float rv_sh[256];
    __shared__ int   ri_sh[256];

    const float* resS = res + seq * T_DIM;
    int tid = threadIdx.x;

    for (int i = tid; i < AT * K_DIM; i += 256) du_sh[i] = du[a_base * K_DIM + i];
    for (int i = tid; i < TT + K_DIM - 1; i += 256) {
        int t = t_base + i - K_DIM / 2;
        res_sh[i] = (t >= 0 && t < T_DIM) ? resS[t] : 0.0f;
    }
    __syncthreads();

    int tg = tid & 63;       // time subgroup: lane -> stride-1 LDS access
    int ag = tid >> 6;       // 0..3 atom subgroup (uniform per wave)
    int a0 = ag * 8;

    float acc[8][8];
    #pragma unroll
    for (int i = 0; i < 8; i++)
        #pragma unroll
        for (int j = 0; j < 8; j++) acc[i][j] = 0.0f;

    for (int k = 0; k < K_DIM; k++) {
        float dv[8];
        #pragma unroll
        for (int i = 0; i < 8; i++) dv[i] = du_sh[(a0 + i) * K_DIM + k];  // wave broadcast
        #pragma unroll
        for (int j = 0; j < 8; j++) {
            float rv = res_sh[tg + 64 * j + k];                            // stride-1
            #pragma unroll
            for (int i = 0; i < 8; i++) acc[i][j] = fmaf(dv[i], rv, acc[i][j]);
        }
    }

    // per-thread argmax (flat index = a*T + t, lowest index on tie)
    float bv = -INFINITY;
    int bi = 0x7fffffff;
    #pragma unroll
    for (int i = 0; i < 8; i++) {
        int a = a_base + a0 + i;
        #pragma unroll
        for (int j = 0; j < 8; j++) {
            int t = t_base + tg + 64 * j;
            int fi = a * T_DIM + t;
            float v = acc[i][j];
            if (v > bv || (v == bv && fi < bi)) { bv = v; bi = fi; }
        }
    }

    rv_sh[tid] = bv;
    ri_sh[tid] = bi;
    __syncthreads();
    for (int off = 128; off > 0; off >>= 1) {
        if (tid < off) {
            float v2 = rv_sh[tid + off]; int i2 = ri_sh[tid + off];
            if (v2 > rv_sh[tid] || (v2 == rv_sh[tid] && i2 < ri_sh[tid])) {
                rv_sh[tid] = v2; ri_sh[tid] = i2;
            }
        }
        __syncthreads();
    }
    if (tid == 0) {
        pvals[seq * NB_PER_SEQ + blk] = rv_sh[0];
        pidx[seq * NB_PER_SEQ + blk] = ri_sh[0];
    }
}

// ---------------------------------------------------------------------------
// reduce partials -> (value, fi); emit emb row; subtract atom from res
__global__ void k_finalize(const float* __restrict__ pvals, const int* __restrict__ pidx,
                           const float* __restrict__ du, const float* __restrict__ ae,
                           float* __restrict__ res, float* __restrict__ emb, int step) {
    int seq = blockIdx.x;
    int tid = threadIdx.x;   // 128
    __shared__ float v_sh[128];
    __shared__ int   i_sh[128];
    v_sh[tid] = pvals[seq * NB_PER_SEQ + tid];
    i_sh[tid] = pidx[seq * NB_PER_SEQ + tid];
    __syncthreads();
    for (int off = 64; off > 0; off >>= 1) {
        if (tid < off) {
            float v2 = v_sh[tid + off]; int i2 = i_sh[tid + off];
            if (v2 > v_sh[tid] || (v2 == v_sh[tid] && i2 < i_sh[tid])) {
                v_sh[tid] = v2; i_sh[tid] = i2;
            }
        }
        __syncthreads();
    }
    float value = v_sh[0];
    int fi = i_sh[0];
    int ai = fi >> 14;          // / T_DIM
    int ti = fi & (T_DIM - 1);  // % T_DIM

    // soft_dirac forward == hard one-hot of argmax; if value<=0 argmax of the
    // (zeros + value at idx) row is index 0
    int pos_idx = value > 0.0f ? ti : 0;
    int atom_idx = value > 0.0f ? ai : 0;

    float* e = emb + (seq * N_STEPS + step) * 128;
    if (tid == 0) {
        e[0] = ((float)pos_idx / (float)(T_DIM - 1)) * 20.0f;
        e[1] = value;
    }
    if (tid < E_DIM) e[2 + tid] = ae[atom_idx * E_DIM + tid];

    // res[ti + k - 64] -= value * du[ai, k]
    int t = ti + tid - K_DIM / 2;
    if (t >= 0 && t < T_DIM) res[seq * T_DIM + t] -= value * du[ai * K_DIM + tid];
}

// ---------------------------------------------------------------------------
__global__ void k_norms(const float* __restrict__ res, float* __restrict__ norms) {
    int seq = blockIdx.x;
    int tid = threadIdx.x;   // 256
    float s = 0.0f;
    for (int i = tid; i < T_DIM; i += 256) {
        float v = res[seq * T_DIM + i];
        s = fmaf(v, v, s);
    }
    __shared__ float sh[256];
    sh[tid] = s;
    __syncthreads();
    for (int off = 128; off > 0; off >>= 1) {
        if (tid < off) sh[tid] += sh[tid + off];
        __syncthreads();
    }
    if (tid == 0) norms[seq] = sqrtf(sh[0]);
}

__global__ void k_loss(const float* __restrict__ emb, const float* __restrict__ proj,
                       const float* __restrict__ norms, float* __restrict__ out) {
    __shared__ float keys[NSEQ][N_STEPS];
    __shared__ int   order[NSEQ][N_STEPS];
    int tid = threadIdx.x;  // 256
    if (tid < NSEQ * N_STEPS) {
        int seq = tid / N_STEPS, s = tid % N_STEPS;
        const float* e = emb + (seq * N_STEPS + s) * 128;
        float k = 0.0f;
        for (int d = 0; d < 128; d++) k = fmaf(e[d], proj[d], k);
        keys[seq][s] = k;
    }
    __syncthreads();
    if (tid < NSEQ) {
        int ord[N_STEPS];
        for (int i = 0; i < N_STEPS; i++) ord[i] = i;
        for (int i = 1; i < N_STEPS; i++) {      // stable insertion sort, ascending
            int oi = ord[i];
            float kv = keys[tid][oi];
            int j = i - 1;
            while (j >= 0 && keys[tid][ord[j]] > kv) { ord[j + 1] = ord[j]; j--; }
            ord[j + 1] = oi;
        }
        for (int i = 0; i < N_STEPS; i++) order[tid][i] = ord[i];
    }
    __syncthreads();
    float s = 0.0f;
    for (int idx = tid; idx < 2 * N_STEPS * 128; idx += 256) {
        int b = idx / (N_STEPS * 128);
        int st = (idx / 128) % N_STEPS;
        int d = idx % 128;
        float va = emb[((b    ) * N_STEPS + order[b    ][st]) * 128 + d];
        float vb = emb[((2 + b) * N_STEPS + order[2 + b][st]) * 128 + d];
        float df = va - vb;
        s = fmaf(df, df, s);
    }
    __shared__ float sh[256];
    sh[tid] = s;
    __syncthreads();
    for (int off = 128; off > 0; off >>= 1) {
        if (tid < off) sh[tid] += sh[tid + off];
        __syncthreads();
    }
    if (tid == 0) {
        float mse = sh[0] / (float)(2 * N_STEPS * 128);
        float mad = 0.5f * (fabsf(norms[0] - norms[2]) + fabsf(norms[1] - norms[3]));
        out[0] = mse + mad;
    }
}

// ---------------------------------------------------------------------------
extern "C" void kernel_launch(void* const* d_in, const int* in_sizes, int n_in,
                              void* d_out, int out_size, void* d_ws, size_t ws_size,
                              hipStream_t stream) {
    const float* a    = (const float*)d_in[0];
    const float* b    = (const float*)d_in[1];
    const float* d    = (const float*)d_in[2];
    const float* ae   = (const float*)d_in[3];
    const float* proj = (const float*)d_in[4];
    float* out = (float*)d_out;

    float* ws    = (float*)d_ws;
    float* res   = ws;                          // 4*16384 = 65536
    float* du    = res + NSEQ * T_DIM;          // 16384
    float* emb   = du + A_DIM * K_DIM;          // 4*16*128 = 8192
    float* pvals = emb + NSEQ * N_STEPS * 128;  // 4*128 = 512
    float* norms = pvals + NSEQ * NB_PER_SEQ;   // 4
    int*   pidx  = (int*)(norms + 4);           // 4*128 ints

    k_dunit<<<A_DIM, K_DIM, 0, stream>>>(d, du);
    k_init<<<(NSEQ * T_DIM + 255) / 256, 256, 0, stream>>>(a, b, res);

    for (int step = 0; step < N_STEPS; step++) {
        dim3 grid(NB_PER_SEQ, NSEQ);
        k_fm_argmax<<<grid, 256, 0, stream>>>(res, du, pvals, pidx);
        k_finalize<<<NSEQ, 128, 0, stream>>>(pvals, pidx, du, ae, res, emb, step);
    }

    k_norms<<<NSEQ, 256, 0, stream>>>(res, norms);
    k_loss<<<1, 256, 0, stream>>>(emb, proj, norms, out);
}